// Round 7
// baseline (191.644 us; speedup 1.0000x reference)
//
#include <hip/hip_runtime.h>
#include <hip/hip_bf16.h>

// Sizes (fixed): B=2, S=2048, D=1024, H=16, Hd=64
#define SEQ    2048
#define DMODEL 1024
#define NHEAD  16
#define HDIM   64
#define BATCH  2
#define NTOK   (BATCH * SEQ)           // 4096

#define N_X   (NTOK * DMODEL)
#define N_WQ  (3 * DMODEL * DMODEL)
#define N_BQ  (3 * DMODEL)
#define N_WO  (DMODEL * DMODEL)
#define N_BO  (DMODEL)
#define N_CANON (N_X + N_WQ + N_BQ + N_WO + N_BO)   // 8,392,704

#define NEG_SENT (-1.0e30f)
#define QSCALE 0.1803368801111f        // (1/8) * log2(e)

typedef __attribute__((ext_vector_type(8))) short short8;
typedef __attribute__((ext_vector_type(4))) short short4v;
typedef __attribute__((ext_vector_type(4))) float f32x4;

#define MFMA_BF16(A, B, C) __builtin_amdgcn_mfma_f32_16x16x32_bf16((A), (B), (C), 0, 0, 0)

static __device__ __forceinline__ short8 load8(const __hip_bfloat16* p) {
    return *(const short8*)p;
}

static __device__ __forceinline__ void async16(const void* g, void* l) {
    __builtin_amdgcn_global_load_lds(
        (const __attribute__((address_space(1))) unsigned int*)g,
        (__attribute__((address_space(3))) unsigned int*)l,
        16, 0, 0);
}

// ---------------------------------------------------------------------------
// Kernel 0: dtype detector
// ---------------------------------------------------------------------------
__global__ void detect_kernel(const unsigned short* __restrict__ w, int* flag) {
    int cnt = 0;
    for (int i = threadIdx.x; i < 512; i += 64) {
        const unsigned e = (w[i] >> 7) & 0xFF;
        if (e >= 125) cnt++;
    }
#pragma unroll
    for (int o = 32; o; o >>= 1) cnt += __shfl_down(cnt, o);
    if (threadIdx.x == 0) *flag = (cnt > 8) ? 1 : 0;
}

// ---------------------------------------------------------------------------
// Kernel 0b: canonicalize inputs to bf16, vectorized 8 elems/thread.
// ---------------------------------------------------------------------------
__global__ __launch_bounds__(256) void canon_kernel(
    const void* __restrict__ s0, const void* __restrict__ s1,
    const void* __restrict__ s2, const void* __restrict__ s3,
    const void* __restrict__ s4,
    __hip_bfloat16* __restrict__ dst, const int* __restrict__ flag)
{
    const int v = blockIdx.x * 256 + threadIdx.x;
    if (v >= N_CANON / 8) return;
    const int idx = v * 8;
    const void* src;
    int off;
    if (idx < N_X)                          { src = s0; off = idx; }
    else if (idx < N_X + N_WQ)              { src = s1; off = idx - N_X; }
    else if (idx < N_X + N_WQ + N_BQ)       { src = s2; off = idx - (N_X + N_WQ); }
    else if (idx < N_X + N_WQ + N_BQ + N_WO){ src = s3; off = idx - (N_X + N_WQ + N_BQ); }
    else                                    { src = s4; off = idx - (N_X + N_WQ + N_BQ + N_WO); }
    if (*flag != 0) {
        const f32x4* sp = (const f32x4*)((const float*)src + off);
        const f32x4 x0 = sp[0], x1 = sp[1];
        short8 o;
#pragma unroll
        for (int j = 0; j < 4; ++j) {
            o[j]     = (short)__bfloat16_as_ushort(__float2bfloat16(x0[j]));
            o[4 + j] = (short)__bfloat16_as_ushort(__float2bfloat16(x1[j]));
        }
        *(short8*)&dst[idx] = o;
    } else {
        *(short8*)&dst[idx] = *(const short8*)((const __hip_bfloat16*)src + off);
    }
}

// ---------------------------------------------------------------------------
// Kernel 1: QKV GEMM, m97 structure + T2 swizzle + 3-BUFFER RING (round 16):
// single barrier per K-step (attn-R4 pattern), staging runs 2 tiles ahead,
// counted vmcnt(4) never drains mid-loop.  LDS 48KB -> 3 WGs/CU kept.
// ---------------------------------------------------------------------------
__global__ __launch_bounds__(256) void qkv_gemm_kernel(
    const __hip_bfloat16* __restrict__ X,
    const __hip_bfloat16* __restrict__ W,
    const __hip_bfloat16* __restrict__ bias,
    __hip_bfloat16* __restrict__ Qs,
    __hip_bfloat16* __restrict__ Kb,
    __hip_bfloat16* __restrict__ Vt)
{
    constexpr int Kd = DMODEL;
    __shared__ __align__(16) __hip_bfloat16 As[3][128 * 32];
    __shared__ __align__(16) __hip_bfloat16 Bs[3][128 * 32];

    const int tid   = threadIdx.x;
    const int lane  = tid & 63;
    const int w     = tid >> 6;
    const int mTile = blockIdx.y * 128;
    const int nTile = blockIdx.x * 128;
    const int wm    = (w >> 1) * 64;
    const int wn    = (w & 1) * 64;
    const int lm    = lane & 15;
    const int q4    = lane >> 4;
    const int lks   = (q4 ^ ((lm >> 1) & 3)) * 8;

    f32x4 acc[4][4];
#pragma unroll
    for (int i = 0; i < 4; ++i)
#pragma unroll
        for (int j = 0; j < 4; ++j)
            acc[i][j] = (f32x4){0.f, 0.f, 0.f, 0.f};

    const int r0c = tid >> 2;
    const int r1c = (tid + 256) >> 2;
    const int cbs = ((tid & 3) ^ ((tid >> 3) & 3)) * 8;

    const __hip_bfloat16* gA0 = &X[(size_t)(mTile + r0c) * Kd + cbs];
    const __hip_bfloat16* gA1 = &X[(size_t)(mTile + r1c) * Kd + cbs];
    const __hip_bfloat16* gB0 = &W[(size_t)(nTile + r0c) * Kd + cbs];
    const __hip_bfloat16* gB1 = &W[(size_t)(nTile + r1c) * Kd + cbs];

    // prologue: stage k-steps 0,1 into buffers 0,1
    async16(gA0, (char*)As[0] + tid * 16);
    async16(gA1, (char*)As[0] + tid * 16 + 4096);
    async16(gB0, (char*)Bs[0] + tid * 16);
    async16(gB1, (char*)Bs[0] + tid * 16 + 4096);
    async16(gA0 + 32, (char*)As[1] + tid * 16);
    async16(gA1 + 32, (char*)As[1] + tid * 16 + 4096);
    async16(gB0 + 32, (char*)Bs[1] + tid * 16);
    async16(gB1 + 32, (char*)Bs[1] + tid * 16 + 4096);

    int cur = 0;
    constexpr int NIT = Kd / 32;
    for (int it = 0; it < NIT; ++it) {
        if (it + 1 < NIT) {
            asm volatile("s_waitcnt vmcnt(4)" ::: "memory");
        } else {
            asm volatile("s_waitcnt vmcnt(0)" ::: "memory");
        }
        __builtin_amdgcn_s_barrier();          // buf[cur] ready; prev reads done
        __builtin_amdgcn_sched_barrier(0);

        if (it + 2 < NIT) {                    // stage it+2 (overlaps compute)
            const int slot = (cur + 2 >= 3) ? cur - 1 : cur + 2;
            const int k2 = (it + 2) * 32;
            async16(gA0 + k2, (char*)As[slot] + tid * 16);
            async16(gA1 + k2, (char*)As[slot] + tid * 16 + 4096);
            async16(gB0 + k2, (char*)Bs[slot] + tid * 16);
            async16(gB1 + k2, (char*)Bs[slot] + tid * 16 + 4096);
        }

        const __hip_bfloat16* Ac = As[cur];
        const __hip_bfloat16* Bc = Bs[cur];
        short8 a[4], b[4];
#pragma unroll
        for (int i = 0; i < 4; ++i)
            a[i] = *(const short8*)&Ac[(wm + i * 16 + lm) * 32 + lks];
#pragma unroll
        for (int j = 0; j < 4; ++j)
            b[j] = *(const short8*)&Bc[(wn + j * 16 + lm) * 32 + lks];
#pragma unroll
        for (int i = 0; i < 4; ++i)
#pragma unroll
            for (int j = 0; j < 4; ++j)
                acc[i][j] = MFMA_BF16(a[i], b[j], acc[i][j]);

        cur = (cur + 1 == 3) ? 0 : cur + 1;
    }

    const int r0 = (lane >> 4) * 4;
#pragma unroll
    for (int j = 0; j < 4; ++j) {
        const int n  = nTile + wn + j * 16 + lm;
        const float bv = __bfloat162float(bias[n]);
        const int c = n >> 10;
        const int h = (n >> 6) & 15;
        const int d = n & 63;
#pragma unroll
        for (int i = 0; i < 4; ++i) {
            if (c == 2) {
                const int m0 = mTile + wm + i * 16 + r0;
                const int bb = m0 >> 11;
                const int s0 = m0 & (SEQ - 1);
                const int bh = bb * NHEAD + h;
                short4v pk;
#pragma unroll
                for (int r = 0; r < 4; ++r)
                    pk[r] = (short)__bfloat16_as_ushort(
                        __float2bfloat16(acc[i][j][r] + bv));
                *(short4v*)&Vt[(size_t)(bh * HDIM + d) * SEQ + s0] = pk;
            } else {
#pragma unroll
                for (int r = 0; r < 4; ++r) {
                    const int m  = mTile + wm + i * 16 + r0 + r;
                    const int bb = m >> 11;
                    const int s  = m & (SEQ - 1);
                    const int bh = bb * NHEAD + h;
                    const float v = acc[i][j][r] + bv;
                    if (c == 0) {
                        Qs[(size_t)(bh * SEQ + s) * HDIM + d] = __float2bfloat16(v * QSCALE);
                    } else {
                        Kb[(size_t)(bh * SEQ + s) * HDIM + d] = __float2bfloat16(v);
                    }
                }
            }
        }
    }
}

// ---------------------------------------------------------------------------
// Kernel 2: cooperative causal flash attention, 3-way split-K pair-balanced,
// 32 Q-ROWS PER WAVE (round 16).
//
// Round-15 diagnosis: LDS-bandwidth-bound (~73% LDS-pipe busy) — each wave
// reads the full 8KB K + 8KB V tile per chunk regardless of how many q-rows
// it owns.  4 waves x 32 rows (256 thr) instead of 8 x 16 cuts LDS bytes
// per q-row by 40% (24KB/32rows vs 40KB/32rows).  VALU+MFMA per row equal.
// Same 768-WG grid (3 WGs/CU), same XCD clustering, same split-K segments.
// ---------------------------------------------------------------------------
#define P_PITCH 72
__global__ __launch_bounds__(256, 3) void attn_kernel(
    const __hip_bfloat16* __restrict__ Qs,  // [B,H,S,Hd], pre-scaled
    const __hip_bfloat16* __restrict__ Kb,  // [B,H,S,Hd]
    const __hip_bfloat16* __restrict__ Vt,  // [B,H,Hd,S]
    float* __restrict__ Opart,              // [32 bh][8 p][5 slot][128][64] f32
    float* __restrict__ MLpart)             // [32 bh][8 p][5 slot][128][2] f32
{
    __shared__ __align__(16) __hip_bfloat16 Kt[2][64 * 64];
    __shared__ __align__(16) __hip_bfloat16 Vs[2][64 * 64];
    __shared__ __align__(16) __hip_bfloat16 Pall[4][32 * P_PITCH];

    const int tid  = threadIdx.x;
    const int lane = tid & 63;
    const int wv   = tid >> 6;              // 0..3
    const int bh   = blockIdx.x;            // XCD = bh % 8
    const int py   = blockIdx.y;            // 0..23
    const int p    = py / 3;                // pair index 0..7
    const int j3   = py % 3;                // third index 0..2

    const int c_lo = (j3 == 0) ? 0 : (j3 == 1 ? 12 : 23);
    const int c_hi = (j3 == 0) ? 12 : (j3 == 1 ? 23 : 34);
    const int bnd  = 32 - 2 * p;            // heavy block's chunk count

    const int lm  = lane & 15;
    const int q4  = lane >> 4;
    const int lk  = q4 * 8;
    const int swz = (lm & 3) << 4;

    __hip_bfloat16* P = Pall[wv];

    const __hip_bfloat16* Qbh = Qs + (size_t)bh * SEQ * HDIM;
    const __hip_bfloat16* Kbh = Kb + (size_t)bh * SEQ * HDIM;
    const __hip_bfloat16* Vbh = Vt + (size_t)bh * HDIM * SEQ;

    // staging: 256 threads, each stages rows (tid>>3) and (tid>>3)+32,
    // 16B column-block (tid&7), XOR-swizzled by row&7 (same for both rows).
    const int srow0 = tid >> 3;             // 0..31
    const int scb   = (tid & 7) ^ (srow0 & 7);

    for (int seg = 0; seg < 2; ++seg) {
        int qb, a, b, slot;
        if (seg == 0) {                      // heavy block qb = 15-p
            if (j3 == 2 && p >= 5) continue; // empty
            qb = 15 - p; a = c_lo;
            b  = (c_hi < bnd) ? c_hi : bnd;
            slot = j3;                       // 0,1,2
        } else {                             // light block qb = p
            if (j3 == 0 || (j3 == 1 && p <= 4)) continue; // empty
            qb = p;
            a  = ((c_lo > bnd) ? c_lo : bnd) - bnd;
            b  = c_hi - bnd;
            slot = (j3 == 2) ? 3 : 4;
        }

        const int wbase = qb * 128 + wv * 32;   // this wave's 32 q-rows

        short8 qa[2][2];
#pragma unroll
        for (int i = 0; i < 2; ++i)
#pragma unroll
            for (int h = 0; h < 2; ++h)
                qa[i][h] = load8(&Qbh[(size_t)(wbase + i * 16 + lm) * HDIM + h * 32 + lk]);

        float m_run[2] = {NEG_SENT, NEG_SENT};
        float l_run[2] = {0.f, 0.f};
        f32x4 Oacc[2][4];
#pragma unroll
        for (int i = 0; i < 2; ++i)
#pragma unroll
            for (int t = 0; t < 4; ++t) Oacc[i][t] = (f32x4){0.f, 0.f, 0.f, 0.f};

        // protect ring buffers from the previous segment's in-flight reads
        __builtin_amdgcn_s_barrier();

        // prologue: stage chunks a, a+1 into buffers 0,1 (4 loads each)
        {
            const int kk0 = a * 64;
            async16(&Kbh[(size_t)(kk0 + srow0) * HDIM + scb * 8],      (char*)Kt[0] + tid * 16);
            async16(&Kbh[(size_t)(kk0 + srow0 + 32) * HDIM + scb * 8], (char*)Kt[0] + tid * 16 + 4096);
            async16(&Vbh[(size_t)srow0 * SEQ + kk0 + scb * 8],         (char*)Vs[0] + tid * 16);
            async16(&Vbh[(size_t)(srow0 + 32) * SEQ + kk0 + scb * 8],  (char*)Vs[0] + tid * 16 + 4096);
            if (a + 1 < b) {
                const int kk1 = kk0 + 64;
                async16(&Kbh[(size_t)(kk1 + srow0) * HDIM + scb * 8],      (char*)Kt[1] + tid * 16);
                async16(&Kbh[(size_t)(kk1 + srow0 + 32) * HDIM + scb * 8], (char*)Kt[1] + tid * 16 + 4096);
                async16(&Vbh[(size_t)srow0 * SEQ + kk1 + scb * 8],         (char*)Vs[1] + tid * 16);
                async16(&Vbh[(size_t)(srow0 + 32) * SEQ + kk1 + scb * 8],  (char*)Vs[1] + tid * 16 + 4096);
            }
        }

        int cur = 0;
        for (int ci = a; ci < b; ++ci) {
            const int k0 = ci * 64;

            if (ci + 1 < b) {
                asm volatile("s_waitcnt vmcnt(4)" ::: "memory");
            } else {
                asm volatile("s_waitcnt vmcnt(0)" ::: "memory");
            }
            __builtin_amdgcn_s_barrier();          // chunk ci visible
            __builtin_amdgcn_sched_barrier(0);

            if (k0 <= wbase + 31) {   // not fully masked for this wave
                const __hip_bfloat16* Kc = Kt[cur];
                const __hip_bfloat16* Vc = Vs[cur];

                short8 ka[4][2];
#pragma unroll
                for (int t = 0; t < 4; ++t)
#pragma unroll
                    for (int h = 0; h < 2; ++h)
                        ka[t][h] = *(const short8*)&Kc[(t * 16 + lm) * 64 +
                                                       (((h * 4 + q4) ^ (lm & 7)) * 8)];

                f32x4 sc[2][4];
#pragma unroll
                for (int i = 0; i < 2; ++i)
#pragma unroll
                    for (int t = 0; t < 4; ++t) sc[i][t] = (f32x4){0.f, 0.f, 0.f, 0.f};
#pragma unroll
                for (int t = 0; t < 4; ++t)
#pragma unroll
                    for (int i = 0; i < 2; ++i) {
                        sc[i][t] = MFMA_BF16(ka[t][0], qa[i][0], sc[i][t]);
                        sc[i][t] = MFMA_BF16(ka[t][1], qa[i][1], sc[i][t]);
                    }

                if (k0 + 63 > wbase) {
#pragma unroll
                    for (int i = 0; i < 2; ++i) {
                        const int row = wbase + i * 16 + lm;
#pragma unroll
                        for (int t = 0; t < 4; ++t)
#pragma unroll
                            for (int r = 0; r < 4; ++r) {
                                const int key = k0 + t * 16 + q4 * 4 + r;
                                if (key > row) sc[i][t][r] = NEG_SENT;
                            }
                    }
                }

#pragma unroll
                for (int i = 0; i < 2; ++i) {
                    float mx = sc[i][0][0];
#pragma unroll
                    for (int t = 0; t < 4; ++t)
#pragma unroll
                        for (int r = 0; r < 4; ++r) mx = fmaxf(mx, sc[i][t][r]);
                    mx = fmaxf(mx, __shfl_xor(mx, 16));
                    mx = fmaxf(mx, __shfl_xor(mx, 32));

                    // defer-max (T13)
                    if (!__all(mx <= m_run[i] + 8.0f)) {
                        const float mn = fmaxf(m_run[i], mx);
                        const float alpha = exp2f(m_run[i] - mn);
                        m_run[i] = mn;
                        l_run[i] *= alpha;
#pragma unroll
                        for (int r = 0; r < 4; ++r) {
                            const float av = __shfl(alpha, q4 * 4 + r);
#pragma unroll
                            for (int t = 0; t < 4; ++t) Oacc[i][t][r] *= av;
                        }
                    }

                    float s = 0.f;
#pragma unroll
                    for (int t = 0; t < 4; ++t)
#pragma unroll
                        for (int r = 0; r < 4; ++r) {
                            const float pv = exp2f(sc[i][t][r] - m_run[i]);
                            sc[i][t][r] = pv;
                            s += pv;
                        }
                    s += __shfl_xor(s, 16);
                    s += __shfl_xor(s, 32);
                    l_run[i] += s;
                }

#pragma unroll
                for (int i = 0; i < 2; ++i)
#pragma unroll
                    for (int t = 0; t < 4; ++t) {
                        short4v pk;
#pragma unroll
                        for (int r = 0; r < 4; ++r)
                            pk[r] = (short)__bfloat16_as_ushort(__float2bfloat16(sc[i][t][r]));
                        const int col = (t * 16 + q4 * 4) ^ swz;
                        *(short4v*)&P[(i * 16 + lm) * P_PITCH + col] = pk;
                    }

#pragma unroll
                for (int h = 0; h < 2; ++h) {
                    short8 pa[2];
#pragma unroll
                    for (int i = 0; i < 2; ++i)
                        pa[i] = *(const short8*)&P[(i * 16 + lm) * P_PITCH + ((h * 32 + lk) ^ swz)];
#pragma unroll
                    for (int t = 0; t < 4; ++t) {
                        const short8 vb = *(const short8*)&Vc[(t * 16 + lm) * 64 +
                                                              (((h * 4 + q4) ^ (lm & 7)) * 8)];
#pragma unroll
                        for (int i = 0; i < 2; ++i)
                            Oacc[i][t] = MFMA_BF16(pa[i], vb, Oacc[i][t]);
                    }
                }
            }

            __builtin_amdgcn_s_barrier();   // all waves done reading buf[cur]
            if (ci + 2 < b) {               // stage chunk ci+2 into freed buf
                const int kk = (ci + 2) * 64;
                async16(&Kbh[(size_t)(kk + srow0) * HDIM + scb * 8],      (char*)Kt[cur] + tid * 16);
                async16(&Kbh[(size_t)(kk + srow0 + 32) * HDIM + scb * 8], (char*)Kt[cur] + tid * 16 + 4096);
                async16(&Vbh[(size_t)srow0 * SEQ + kk + scb * 8],         (char*)Vs[cur] + tid * 16);
                async16(&Vbh[(size_t)(srow0 + 32) * SEQ + kk + scb * 8],  (char*)Vs[cur] + tid * 16 + 4096);
            }
            cur ^= 1;
        }

        // --- epilogue: store f32 partials for this segment ---
        const size_t pbase = ((size_t)(bh * 8 + p) * 5 + slot) * 128;
#pragma unroll
        for (int i = 0; i < 2; ++i)
#pragma unroll
            for (int t = 0; t < 4; ++t)
#pragma unroll
                for (int r = 0; r < 4; ++r)
                    Opart[(pbase + wv * 32 + i * 16 + q4 * 4 + r) * 64 + t * 16 + lm] = Oacc[i][t][r];
        if (lane < 16) {
#pragma unroll
            for (int i = 0; i < 2; ++i) {
                MLpart[(pbase + wv * 32 + i * 16 + lane) * 2 + 0] = m_run[i];
                MLpart[(pbase + wv * 32 + i * 16 + lane) * 2 + 1] = l_run[i];
            }
        }
    }
}

// ---------------------------------------------------------------------------
// Kernel 2b: merge up to 3 partials per row, normalize, write bf16.
// ---------------------------------------------------------------------------
__global__ __launch_bounds__(256) void attn_merge_kernel(
    const float* __restrict__ Opart, const float* __restrict__ MLpart,
    __hip_bfloat16* __restrict__ O)
{
    const int idx  = blockIdx.x * 256 + threadIdx.x;
    const int d16  = idx & 3;
    const int grow = idx >> 2;             // bh*2048 + s
    const int bh   = grow >> 11;
    const int s    = grow & 2047;
    const int qb   = s >> 7;
    const int rin  = s & 127;

    const bool heavy = (qb >= 8);
    const int p  = heavy ? (15 - qb) : qb;
    const int s0 = heavy ? 0 : 3;
    const int s1 = heavy ? 1 : 4;
    const bool v1 = heavy ? true : (p >= 5);
    const bool v2 = heavy && (p <= 4);     // slot 2

    const size_t rb = (size_t)(bh * 8 + p) * 5;
    const size_t r0 = (rb + s0) * 128 + rin;
    const size_t r1 = (rb + s1) * 128 + rin;
    const size_t r2 = (rb + 2)  * 128 + rin;

    const float m0 = MLpart[r0 * 2],                 l0 = MLpart[r0 * 2 + 1];
    const float m1 = v1 ? MLpart[r1 * 2] : NEG_SENT, l1 = v1 ? MLpart[r1 * 2 + 1] : 0.f;
    const float m2 = v2 ? MLpart[r2 * 2] : NEG_SENT, l2 = v2 ? MLpart[r2 * 2 + 1] : 0.f;

    float mm = fmaxf(m0, fmaxf(m1, m2));
    const float a0 = exp2f(m0 - mm);
    const float a1 = v1 ? exp2f(m1 - mm) : 0.f;
    const float a2 = v2 ? exp2f(m2 - mm) : 0.f;
    const float inv = 1.0f / (a0 * l0 + a1 * l1 + a2 * l2);

    f32x4 o[4];
    {
        const f32x4* O0 = (const f32x4*)&Opart[r0 * 64 + d16 * 16];
#pragma unroll
        for (int v = 0; v < 4; ++v) o[v] = a0 * O0[v];
    }
    if (v1) {
        const f32x4* O1 = (const f32x4*)&Opart[r1 * 64 + d16 * 16];
#pragma unroll
        for (int v = 0; v < 4; ++v) o[v] += a1 * O1[v];
    }
    if (v2) {
        const f32x4* O2 = (const f32x4*)&Opart[r2 * 64 + d16 * 16];
#pragma unroll
        for (int v = 0; v < 4; ++v) o[v] += a2 * O2[v];
    }

    short8 out[2];
#pragma unroll
    for (int v = 0; v < 4; ++v)
#pragma unroll
        for (int jj = 0; jj < 4; ++jj)
            out[v >> 1][(v & 1) * 4 + jj] = (short)__bfloat16_as_ushort(
                __float2bfloat16(o[v][jj] * inv));

    const int b = bh >> 4, hh = bh & 15;
    __hip_bfloat16* dst = &O[((size_t)b * SEQ + s) * DMODEL + hh * 64 + d16 * 16];
    ((short8*)dst)[0] = out[0];
    ((short8*)dst)[1] = out[1];
}

// ---------------------------------------------------------------------------
// Kernel 3: out projection, 128x64 tiles, T2 swizzle + 3-BUFFER RING.
// ---------------------------------------------------------------------------
__global__ __launch_bounds__(256) void proj_gemm_kernel(
    const __hip_bfloat16* __restrict__ A,
    const __hip_bfloat16* __restrict__ W,
    const __hip_bfloat16* __restrict__ bias,
    void* __restrict__ outv,
    const int* __restrict__ flag)
{
    constexpr int Kd = DMODEL;
    __shared__ __align__(16) __hip_bfloat16 As[3][128 * 32];
    __shared__ __align__(16) __hip_bfloat16 Bs[3][64 * 32];

    const int tid   = threadIdx.x;
    const int lane  = tid & 63;
    const int w     = tid >> 6;
    const int mTile = blockIdx.y * 128;
    const int nTile = blockIdx.x * 64;
    const int wm    = (w >> 1) * 64;
    const int wn    = (w & 1) * 32;
    const int lm    = lane & 15;
    const int q4    = lane >> 4;
    const int lks   = (q4 ^ ((lm >> 1) & 3)) * 8;
    const bool f32out = (*flag != 0);

    f32x4 acc[4][2];
#pragma unroll
    for (int i = 0; i < 4; ++i)
#pragma unroll
        for (int j = 0; j < 2; ++j)
            acc[i][j] = (f32x4){0.f, 0.f, 0.f, 0.f};

    const int r0c = tid >> 2;
    const int r1c = (tid + 256) >> 2;
    const int cbs = ((tid & 3) ^ ((tid >> 3) & 3)) * 8;

    const __hip_bfloat16* gA0 = &A[(size_t)(mTile + r0c) * Kd + cbs];
    const __hip_bfloat16* gA1 = &A[(size_t)(mTile + r1c) * Kd + cbs];
    const __hip_bfloat16* gB0 = &W[(size_t)(nTile + r0c) * Kd + cbs];

    async16(gA0, (char*)As[0] + tid * 16);
    async16(gA1, (char*)As[0] + tid * 16 + 4096);
    async16(gB0, (char*)Bs[0] + tid * 16);
    async16(gA0 + 32, (char*)As[1] + tid * 16);
    async16(gA1 + 32, (char*)As[1] + tid * 16 + 4096);
    async16(gB0 + 32, (char*)Bs[1] + tid * 16);

    int cur = 0;
    constexpr int NIT = Kd / 32;
    for (int it = 0; it < NIT; ++it) {
        if (it + 1 < NIT) {
            asm volatile("s_waitcnt vmcnt(3)" ::: "memory");
        } else {
            asm volatile("s_waitcnt vmcnt(0)" ::: "memory");
        }
        __builtin_amdgcn_s_barrier();
        __builtin_amdgcn_sched_barrier(0);

        if (it + 2 < NIT) {
            const int slot = (cur + 2 >= 3) ? cur - 1 : cur + 2;
            const int k2 = (it + 2) * 32;
            async16(gA0 + k2, (char*)As[slot] + tid * 16);
            async16(gA1 + k2, (char*)As[slot] + tid * 16 + 4096);
            async16(gB0 + k2, (char*)Bs[slot] + tid * 16);
        }

        const __hip_bfloat16* Ac = As[cur];
        const __hip_bfloat16* Bc = Bs[cur];
        short8 a[4], b[2];
#pragma unroll
        for (int i = 0; i < 4; ++i)
            a[i] = *(const short8*)&Ac[(wm + i * 16 + lm) * 32 + lks];
#pragma unroll
        for (int j = 0; j < 2; ++j)
            b[j] = *(const short8*)&Bc[(wn + j * 16 + lm) * 32 + lks];
#pragma unroll
        for (int i = 0; i < 4; ++i)
#pragma unroll
            for (int j = 0; j < 2; ++j)
                acc[i][j] = MFMA_BF16(a[i], b[j], acc[i][j]);

        cur = (cur + 1 == 3) ? 0 : cur + 1;
    }

    const int r0 = (lane >> 4) * 4;
#pragma unroll
    for (int j = 0; j < 2; ++j) {
        const int n = nTile + wn + j * 16 + lm;
        const float bv = __bfloat162float(bias[n]);
#pragma unroll
        for (int i = 0; i < 4; ++i) {
#pragma unroll
            for (int r = 0; r < 4; ++r) {
                const size_t m = mTile + wm + i * 16 + r0 + r;
                const float v = acc[i][j][r] + bv;
                if (f32out) ((float*)outv)[m * DMODEL + n] = v;
                else ((__hip_bfloat16*)outv)[m * DMODEL + n] = __float2bfloat16(v);
            }
        }
    }
}

// ---------------------------------------------------------------------------
extern "C" void kernel_launch(void* const* d_in, const int* in_sizes, int n_in,
                              void* d_out, int out_size, void* d_ws, size_t ws_size,
                              hipStream_t stream) {
    // Workspace layout (bytes):
    // [flag:256][canon bf16][Qs][Kb][Vt][Ao][Opart f32][MLpart f32]
    const size_t OFF_CANON = 256;
    const size_t OFF_QS = OFF_CANON + (size_t)N_CANON * 2;
    const size_t OFF_KB = OFF_QS + (size_t)NTOK * DMODEL * 2;
    const size_t OFF_VT = OFF_KB + (size_t)NTOK * DMODEL * 2;
    const size_t OFF_AO = OFF_VT + (size_t)NTOK * DMODEL * 2;
    const size_t OFF_OP = OFF_AO + (size_t)NTOK * DMODEL * 2;
    const size_t OFF_ML = OFF_OP + (size_t)32 * 8 * 5 * 128 * 64 * 4;  // 41.94 MB

    char* wsb = (char*)d_ws;
    int* flag = (int*)wsb;
    __hip_bfloat16* canon = (__hip_bfloat16*)(wsb + OFF_CANON);
    __hip_bfloat16* Xc = canon;
    __hip_bfloat16* Wq = Xc + N_X;
    __hip_bfloat16* Bq = Wq + N_WQ;
    __hip_bfloat16* Wo = Bq + N_BQ;
    __hip_bfloat16* Bo = Wo + N_WO;
    __hip_bfloat16* Qs = (__hip_bfloat16*)(wsb + OFF_QS);
    __hip_bfloat16* Kb = (__hip_bfloat16*)(wsb + OFF_KB);
    __hip_bfloat16* Vt = (__hip_bfloat16*)(wsb + OFF_VT);
    __hip_bfloat16* Ao = (__hip_bfloat16*)(wsb + OFF_AO);
    float* Opart = (float*)(wsb + OFF_OP);
    float* MLpart = (float*)(wsb + OFF_ML);

    // 0) dtype detect + canonicalize (vectorized, 8 elems/thread)
    detect_kernel<<<1, 64, 0, stream>>>((const unsigned short*)d_in[1], flag);
    canon_kernel<<<(N_CANON / 8 + 255) / 256, 256, 0, stream>>>(
        d_in[0], d_in[1], d_in[2], d_in[3], d_in[4], canon, flag);

    // 1) QKV GEMM (3-buffer ring, 1 barrier/K-step)
    {
        dim3 grid(3 * DMODEL / 128, NTOK / 128);
        qkv_gemm_kernel<<<grid, 256, 0, stream>>>(Xc, Wq, Bq, Qs, Kb, Vt);
    }
    // 2) Attention: 3-way split-K, grid (32 bh, 24) = 768 WGs of 4 waves
    //    x 32 q-rows; 3 WGs/CU; all WGs of a head on one XCD.
    {
        dim3 grid(BATCH * NHEAD, 24);
        attn_kernel<<<grid, 256, 0, stream>>>(Qs, Kb, Vt, Opart, MLpart);
        attn_merge_kernel<<<(NTOK * NHEAD * 4) / 256, 256, 0, stream>>>(
            Opart, MLpart, Ao);
    }
    // 3) Out projection: 128x64 tiles -> 512 WGs (3-buffer ring)
    {
        dim3 grid(DMODEL / 64, NTOK / 128);
        proj_gemm_kernel<<<grid, 256, 0, stream>>>(Ao, Wo, Bo, d_out, flag);
    }
}

// Round 8
// 191.216 us; speedup vs baseline: 1.0022x; 1.0022x over previous
//
#include <hip/hip_runtime.h>
#include <hip/hip_bf16.h>

// Sizes (fixed): B=2, S=2048, D=1024, H=16, Hd=64
#define SEQ    2048
#define DMODEL 1024
#define NHEAD  16
#define HDIM   64
#define BATCH  2
#define NTOK   (BATCH * SEQ)           // 4096

#define N_X   (NTOK * DMODEL)
#define N_WQ  (3 * DMODEL * DMODEL)
#define N_BQ  (3 * DMODEL)
#define N_WO  (DMODEL * DMODEL)
#define N_BO  (DMODEL)
#define N_CANON (N_X + N_WQ + N_BQ + N_WO + N_BO)   // 8,392,704

#define NEG_SENT (-1.0e30f)
#define QSCALE 0.1803368801111f        // (1/8) * log2(e)

typedef __attribute__((ext_vector_type(8))) short short8;
typedef __attribute__((ext_vector_type(4))) short short4v;
typedef __attribute__((ext_vector_type(4))) float f32x4;
typedef __attribute__((ext_vector_type(16))) float f32x16;

#define MFMA_BF16(A, B, C) __builtin_amdgcn_mfma_f32_16x16x32_bf16((A), (B), (C), 0, 0, 0)
#define MFMA32_BF16(A, B, C) __builtin_amdgcn_mfma_f32_32x32x16_bf16((A), (B), (C), 0, 0, 0)

static __device__ __forceinline__ short8 load8(const __hip_bfloat16* p) {
    return *(const short8*)p;
}

static __device__ __forceinline__ unsigned cvtpk_bf16(float lo, float hi) {
    unsigned r;
    asm("v_cvt_pk_bf16_f32 %0, %1, %2" : "=v"(r) : "v"(lo), "v"(hi));
    return r;
}

static __device__ __forceinline__ void async16(const void* g, void* l) {
    __builtin_amdgcn_global_load_lds(
        (const __attribute__((address_space(1))) unsigned int*)g,
        (__attribute__((address_space(3))) unsigned int*)l,
        16, 0, 0);
}

// ---------------------------------------------------------------------------
// Kernel 0: dtype detector
// ---------------------------------------------------------------------------
__global__ void detect_kernel(const unsigned short* __restrict__ w, int* flag) {
    int cnt = 0;
    for (int i = threadIdx.x; i < 512; i += 64) {
        const unsigned e = (w[i] >> 7) & 0xFF;
        if (e >= 125) cnt++;
    }
#pragma unroll
    for (int o = 32; o; o >>= 1) cnt += __shfl_down(cnt, o);
    if (threadIdx.x == 0) *flag = (cnt > 8) ? 1 : 0;
}

// ---------------------------------------------------------------------------
// Kernel 0b: canonicalize inputs to bf16, vectorized 8 elems/thread.
// ---------------------------------------------------------------------------
__global__ __launch_bounds__(256) void canon_kernel(
    const void* __restrict__ s0, const void* __restrict__ s1,
    const void* __restrict__ s2, const void* __restrict__ s3,
    const void* __restrict__ s4,
    __hip_bfloat16* __restrict__ dst, const int* __restrict__ flag)
{
    const int v = blockIdx.x * 256 + threadIdx.x;
    if (v >= N_CANON / 8) return;
    const int idx = v * 8;
    const void* src;
    int off;
    if (idx < N_X)                          { src = s0; off = idx; }
    else if (idx < N_X + N_WQ)              { src = s1; off = idx - N_X; }
    else if (idx < N_X + N_WQ + N_BQ)       { src = s2; off = idx - (N_X + N_WQ); }
    else if (idx < N_X + N_WQ + N_BQ + N_WO){ src = s3; off = idx - (N_X + N_WQ + N_BQ); }
    else                                    { src = s4; off = idx - (N_X + N_WQ + N_BQ + N_WO); }
    if (*flag != 0) {
        const f32x4* sp = (const f32x4*)((const float*)src + off);
        const f32x4 x0 = sp[0], x1 = sp[1];
        short8 o;
#pragma unroll
        for (int j = 0; j < 4; ++j) {
            o[j]     = (short)__bfloat16_as_ushort(__float2bfloat16(x0[j]));
            o[4 + j] = (short)__bfloat16_as_ushort(__float2bfloat16(x1[j]));
        }
        *(short8*)&dst[idx] = o;
    } else {
        *(short8*)&dst[idx] = *(const short8*)((const __hip_bfloat16*)src + off);
    }
}

// ---------------------------------------------------------------------------
// Kernel 1: QKV GEMM, m97 structure + T2 swizzle + 3-buffer ring.
// (unchanged from round 16)
// ---------------------------------------------------------------------------
__global__ __launch_bounds__(256) void qkv_gemm_kernel(
    const __hip_bfloat16* __restrict__ X,
    const __hip_bfloat16* __restrict__ W,
    const __hip_bfloat16* __restrict__ bias,
    __hip_bfloat16* __restrict__ Qs,
    __hip_bfloat16* __restrict__ Kb,
    __hip_bfloat16* __restrict__ Vt)
{
    constexpr int Kd = DMODEL;
    __shared__ __align__(16) __hip_bfloat16 As[3][128 * 32];
    __shared__ __align__(16) __hip_bfloat16 Bs[3][128 * 32];

    const int tid   = threadIdx.x;
    const int lane  = tid & 63;
    const int w     = tid >> 6;
    const int mTile = blockIdx.y * 128;
    const int nTile = blockIdx.x * 128;
    const int wm    = (w >> 1) * 64;
    const int wn    = (w & 1) * 64;
    const int lm    = lane & 15;
    const int q4    = lane >> 4;
    const int lks   = (q4 ^ ((lm >> 1) & 3)) * 8;

    f32x4 acc[4][4];
#pragma unroll
    for (int i = 0; i < 4; ++i)
#pragma unroll
        for (int j = 0; j < 4; ++j)
            acc[i][j] = (f32x4){0.f, 0.f, 0.f, 0.f};

    const int r0c = tid >> 2;
    const int r1c = (tid + 256) >> 2;
    const int cbs = ((tid & 3) ^ ((tid >> 3) & 3)) * 8;

    const __hip_bfloat16* gA0 = &X[(size_t)(mTile + r0c) * Kd + cbs];
    const __hip_bfloat16* gA1 = &X[(size_t)(mTile + r1c) * Kd + cbs];
    const __hip_bfloat16* gB0 = &W[(size_t)(nTile + r0c) * Kd + cbs];
    const __hip_bfloat16* gB1 = &W[(size_t)(nTile + r1c) * Kd + cbs];

    async16(gA0, (char*)As[0] + tid * 16);
    async16(gA1, (char*)As[0] + tid * 16 + 4096);
    async16(gB0, (char*)Bs[0] + tid * 16);
    async16(gB1, (char*)Bs[0] + tid * 16 + 4096);
    async16(gA0 + 32, (char*)As[1] + tid * 16);
    async16(gA1 + 32, (char*)As[1] + tid * 16 + 4096);
    async16(gB0 + 32, (char*)Bs[1] + tid * 16);
    async16(gB1 + 32, (char*)Bs[1] + tid * 16 + 4096);

    int cur = 0;
    constexpr int NIT = Kd / 32;
    for (int it = 0; it < NIT; ++it) {
        if (it + 1 < NIT) {
            asm volatile("s_waitcnt vmcnt(4)" ::: "memory");
        } else {
            asm volatile("s_waitcnt vmcnt(0)" ::: "memory");
        }
        __builtin_amdgcn_s_barrier();          // buf[cur] ready; prev reads done
        __builtin_amdgcn_sched_barrier(0);

        if (it + 2 < NIT) {                    // stage it+2 (overlaps compute)
            const int slot = (cur + 2 >= 3) ? cur - 1 : cur + 2;
            const int k2 = (it + 2) * 32;
            async16(gA0 + k2, (char*)As[slot] + tid * 16);
            async16(gA1 + k2, (char*)As[slot] + tid * 16 + 4096);
            async16(gB0 + k2, (char*)Bs[slot] + tid * 16);
            async16(gB1 + k2, (char*)Bs[slot] + tid * 16 + 4096);
        }

        const __hip_bfloat16* Ac = As[cur];
        const __hip_bfloat16* Bc = Bs[cur];
        short8 a[4], b[4];
#pragma unroll
        for (int i = 0; i < 4; ++i)
            a[i] = *(const short8*)&Ac[(wm + i * 16 + lm) * 32 + lks];
#pragma unroll
        for (int j = 0; j < 4; ++j)
            b[j] = *(const short8*)&Bc[(wn + j * 16 + lm) * 32 + lks];
#pragma unroll
        for (int i = 0; i < 4; ++i)
#pragma unroll
            for (int j = 0; j < 4; ++j)
                acc[i][j] = MFMA_BF16(a[i], b[j], acc[i][j]);

        cur = (cur + 1 == 3) ? 0 : cur + 1;
    }

    const int r0 = (lane >> 4) * 4;
#pragma unroll
    for (int j = 0; j < 4; ++j) {
        const int n  = nTile + wn + j * 16 + lm;
        const float bv = __bfloat162float(bias[n]);
        const int c = n >> 10;
        const int h = (n >> 6) & 15;
        const int d = n & 63;
#pragma unroll
        for (int i = 0; i < 4; ++i) {
            if (c == 2) {
                const int m0 = mTile + wm + i * 16 + r0;
                const int bb = m0 >> 11;
                const int s0 = m0 & (SEQ - 1);
                const int bh = bb * NHEAD + h;
                short4v pk;
#pragma unroll
                for (int r = 0; r < 4; ++r)
                    pk[r] = (short)__bfloat16_as_ushort(
                        __float2bfloat16(acc[i][j][r] + bv));
                *(short4v*)&Vt[(size_t)(bh * HDIM + d) * SEQ + s0] = pk;
            } else {
#pragma unroll
                for (int r = 0; r < 4; ++r) {
                    const int m  = mTile + wm + i * 16 + r0 + r;
                    const int bb = m >> 11;
                    const int s  = m & (SEQ - 1);
                    const int bh = bb * NHEAD + h;
                    const float v = acc[i][j][r] + bv;
                    if (c == 0) {
                        Qs[(size_t)(bh * SEQ + s) * HDIM + d] = __float2bfloat16(v * QSCALE);
                    } else {
                        Kb[(size_t)(bh * SEQ + s) * HDIM + d] = __float2bfloat16(v);
                    }
                }
            }
        }
    }
}

// ---------------------------------------------------------------------------
// Kernel 2: cooperative causal flash attention, 3-way split-K pair-balanced,
// 32x32x16 MFMA + IN-REGISTER P (round 17, m214 structure).
//
// Round-16 diagnosis: aggregate-issue-bound (VALU 48% + LDS + MFMA ~ 90%).
// 32x32 conversion cuts instructions: 16 MFMA -> 8 per chunk; softmax
// lane-local (q = lane&31): 1 shfl_xor(32) per reduce (was 2), alpha
// rescale needs NO broadcast shfls (was 8/chunk); P stays in registers
// via cvt_pk + shfl_xor(32) exchange (T12) -> P LDS buffer deleted
// (51.2KB -> 32KB).  Score layout (verified m101/m214):
//   sc[t][reg] = S[key = k0+t*32+(reg&3)+8*(reg>>2)+4*sg][q = lane&31]
// PV B-frag needs P[q=lane&31][k' = 8*sg + j]; per 16-key step the missing
// half lives in lane^32 -> 2 shfl_xor + 6 selects assemble each fragment.
// ---------------------------------------------------------------------------
__global__ __launch_bounds__(256, 3) void attn_kernel(
    const __hip_bfloat16* __restrict__ Qs,  // [B,H,S,Hd], pre-scaled
    const __hip_bfloat16* __restrict__ Kb,  // [B,H,S,Hd]
    const __hip_bfloat16* __restrict__ Vt,  // [B,H,Hd,S]
    float* __restrict__ Opart,              // [32 bh][8 p][5 slot][128][64] f32
    float* __restrict__ MLpart)             // [32 bh][8 p][5 slot][128][2] f32
{
    __shared__ __align__(16) __hip_bfloat16 Kt[2][64 * 64];
    __shared__ __align__(16) __hip_bfloat16 Vs[2][64 * 64];

    const int tid  = threadIdx.x;
    const int lane = tid & 63;
    const int wv   = tid >> 6;              // 0..3
    const int bh   = blockIdx.x;            // XCD = bh % 8
    const int py   = blockIdx.y;            // 0..23
    const int p    = py / 3;                // pair index 0..7
    const int j3   = py % 3;                // third index 0..2

    const int c_lo = (j3 == 0) ? 0 : (j3 == 1 ? 12 : 23);
    const int c_hi = (j3 == 0) ? 12 : (j3 == 1 ? 23 : 34);
    const int bnd  = 32 - 2 * p;            // heavy block's chunk count

    const int lq = lane & 31;               // q-row within wave's 32
    const int sg = lane >> 5;               // half-wave index
    const int swr = lq & 7;                 // read-side XOR (row & 7)

    const __hip_bfloat16* Qbh = Qs + (size_t)bh * SEQ * HDIM;
    const __hip_bfloat16* Kbh = Kb + (size_t)bh * SEQ * HDIM;
    const __hip_bfloat16* Vbh = Vt + (size_t)bh * HDIM * SEQ;

    // staging: 256 threads, each stages rows (tid>>3) and (tid>>3)+32,
    // 16B column-block (tid&7), XOR-swizzled by row&7 (same for both rows).
    const int srow0 = tid >> 3;             // 0..31
    const int scb   = (tid & 7) ^ (srow0 & 7);

    for (int seg = 0; seg < 2; ++seg) {
        int qb, a, b, slot;
        if (seg == 0) {                      // heavy block qb = 15-p
            if (j3 == 2 && p >= 5) continue; // empty
            qb = 15 - p; a = c_lo;
            b  = (c_hi < bnd) ? c_hi : bnd;
            slot = j3;                       // 0,1,2
        } else {                             // light block qb = p
            if (j3 == 0 || (j3 == 1 && p <= 4)) continue; // empty
            qb = p;
            a  = ((c_lo > bnd) ? c_lo : bnd) - bnd;
            b  = c_hi - bnd;
            slot = (j3 == 2) ? 3 : 4;
        }

        const int wbase = qb * 128 + wv * 32;   // this wave's 32 q-rows
        const int qrow  = wbase + lq;

        // Q fragments (B-operand): Q[q=lq][k = s*16 + sg*8 + j]
        short8 qa[4];
#pragma unroll
        for (int s = 0; s < 4; ++s)
            qa[s] = load8(&Qbh[(size_t)qrow * HDIM + s * 16 + sg * 8]);

        float m_run = NEG_SENT;
        float l_run = 0.f;
        f32x16 Oacc[2];
#pragma unroll
        for (int t = 0; t < 2; ++t)
#pragma unroll
            for (int e = 0; e < 16; ++e) Oacc[t][e] = 0.f;

        // protect ring buffers from the previous segment's in-flight reads
        __builtin_amdgcn_s_barrier();

        // prologue: stage chunks a, a+1 into buffers 0,1 (4 loads each)
        {
            const int kk0 = a * 64;
            async16(&Kbh[(size_t)(kk0 + srow0) * HDIM + scb * 8],      (char*)Kt[0] + tid * 16);
            async16(&Kbh[(size_t)(kk0 + srow0 + 32) * HDIM + scb * 8], (char*)Kt[0] + tid * 16 + 4096);
            async16(&Vbh[(size_t)srow0 * SEQ + kk0 + scb * 8],         (char*)Vs[0] + tid * 16);
            async16(&Vbh[(size_t)(srow0 + 32) * SEQ + kk0 + scb * 8],  (char*)Vs[0] + tid * 16 + 4096);
            if (a + 1 < b) {
                const int kk1 = kk0 + 64;
                async16(&Kbh[(size_t)(kk1 + srow0) * HDIM + scb * 8],      (char*)Kt[1] + tid * 16);
                async16(&Kbh[(size_t)(kk1 + srow0 + 32) * HDIM + scb * 8], (char*)Kt[1] + tid * 16 + 4096);
                async16(&Vbh[(size_t)srow0 * SEQ + kk1 + scb * 8],         (char*)Vs[1] + tid * 16);
                async16(&Vbh[(size_t)(srow0 + 32) * SEQ + kk1 + scb * 8],  (char*)Vs[1] + tid * 16 + 4096);
            }
        }

        int cur = 0;
        for (int ci = a; ci < b; ++ci) {
            const int k0 = ci * 64;

            if (ci + 1 < b) {
                asm volatile("s_waitcnt vmcnt(4)" ::: "memory");
            } else {
                asm volatile("s_waitcnt vmcnt(0)" ::: "memory");
            }
            __builtin_amdgcn_s_barrier();          // chunk ci visible
            __builtin_amdgcn_sched_barrier(0);

            if (k0 <= wbase + 31) {   // not fully masked for this wave
                const __hip_bfloat16* Kc = Kt[cur];
                const __hip_bfloat16* Vc = Vs[cur];

                // ---- QK^T: A = K (rows = keys), B = Q (cols = q) ----
                f32x16 sc[2];
#pragma unroll
                for (int t = 0; t < 2; ++t)
#pragma unroll
                    for (int e = 0; e < 16; ++e) sc[t][e] = 0.f;
#pragma unroll
                for (int t = 0; t < 2; ++t)
#pragma unroll
                    for (int s = 0; s < 4; ++s) {
                        const short8 ka = *(const short8*)&Kc[
                            (t * 32 + lq) * 64 + (((s * 2 + sg) ^ swr) * 8)];
                        sc[t] = MFMA32_BF16(ka, qa[s], sc[t]);
                    }

                // ---- causal mask ----
                if (k0 + 63 > wbase) {
#pragma unroll
                    for (int t = 0; t < 2; ++t)
#pragma unroll
                        for (int g = 0; g < 4; ++g)
#pragma unroll
                            for (int r = 0; r < 4; ++r) {
                                const int key = k0 + t * 32 + r + 8 * g + 4 * sg;
                                if (key > qrow) sc[t][g * 4 + r] = NEG_SENT;
                            }
                }

                // ---- online softmax (row q = lq, split across lane^32) ----
                float mx = sc[0][0];
#pragma unroll
                for (int t = 0; t < 2; ++t)
#pragma unroll
                    for (int e = 0; e < 16; ++e) mx = fmaxf(mx, sc[t][e]);
                mx = fmaxf(mx, __shfl_xor(mx, 32));

                // defer-max (T13)
                if (!__all(mx <= m_run + 8.0f)) {
                    const float mn = fmaxf(m_run, mx);
                    const float alpha = exp2f(m_run - mn);
                    m_run = mn;
                    l_run *= alpha;
#pragma unroll
                    for (int t = 0; t < 2; ++t)
#pragma unroll
                        for (int e = 0; e < 16; ++e) Oacc[t][e] *= alpha;
                }

                float ssum = 0.f;
#pragma unroll
                for (int t = 0; t < 2; ++t)
#pragma unroll
                    for (int e = 0; e < 16; ++e) {
                        const float pv = exp2f(sc[t][e] - m_run);
                        sc[t][e] = pv;
                        ssum += pv;
                    }
                ssum += __shfl_xor(ssum, 32);
                l_run += ssum;

                // ---- pack P to bf16 pairs (16 cvt_pk) ----
                unsigned wpk[2][4][2];
#pragma unroll
                for (int t = 0; t < 2; ++t)
#pragma unroll
                    for (int g = 0; g < 4; ++g) {
                        wpk[t][g][0] = cvtpk_bf16(sc[t][g * 4 + 0], sc[t][g * 4 + 1]);
                        wpk[t][g][1] = cvtpk_bf16(sc[t][g * 4 + 2], sc[t][g * 4 + 3]);
                    }

                // ---- PV: per 16-key step, assemble B-frag in registers ----
#pragma unroll
                for (int s = 0; s < 4; ++s) {
                    const int t  = s >> 1;
                    const int gp = (s & 1) * 2;
                    const unsigned oe0 = wpk[t][gp][0],     oe1 = wpk[t][gp][1];
                    const unsigned oo0 = wpk[t][gp + 1][0], oo1 = wpk[t][gp + 1][1];
                    // sg=0 lanes need partner's even pair; sg=1 need partner's odd.
                    const unsigned pay0 = sg ? oe0 : oo0;
                    const unsigned pay1 = sg ? oe1 : oo1;
                    const unsigned rc0 = (unsigned)__shfl_xor((int)pay0, 32);
                    const unsigned rc1 = (unsigned)__shfl_xor((int)pay1, 32);
                    unsigned f[4];
                    f[0] = sg ? rc0 : oe0;
                    f[1] = sg ? rc1 : oe1;
                    f[2] = sg ? oo0 : rc0;
                    f[3] = sg ? oo1 : rc1;
                    const short8 pa = *(const short8*)f;
#pragma unroll
                    for (int t2 = 0; t2 < 2; ++t2) {
                        const short8 va = *(const short8*)&Vc[
                            (t2 * 32 + lq) * 64 + (((s * 2 + sg) ^ swr) * 8)];
                        Oacc[t2] = MFMA32_BF16(va, pa, Oacc[t2]);
                    }
                }
            }

            __builtin_amdgcn_s_barrier();   // all waves done reading buf[cur]
            if (ci + 2 < b) {               // stage chunk ci+2 into freed buf
                const int kk = (ci + 2) * 64;
                async16(&Kbh[(size_t)(kk + srow0) * HDIM + scb * 8],      (char*)Kt[cur] + tid * 16);
                async16(&Kbh[(size_t)(kk + srow0 + 32) * HDIM + scb * 8], (char*)Kt[cur] + tid * 16 + 4096);
                async16(&Vbh[(size_t)srow0 * SEQ + kk + scb * 8],         (char*)Vs[cur] + tid * 16);
                async16(&Vbh[(size_t)(srow0 + 32) * SEQ + kk + scb * 8],  (char*)Vs[cur] + tid * 16 + 4096);
            }
            cur ^= 1;
        }

        // --- epilogue: store f32 partials for this segment ---
        // Oacc[t2][reg]: q = lq, d = t2*32 + (reg&3) + 8*(reg>>2) + 4*sg
        const size_t pbase = ((size_t)(bh * 8 + p) * 5 + slot) * 128;
        const size_t orow  = (pbase + wv * 32 + lq) * 64;
#pragma unroll
        for (int t2 = 0; t2 < 2; ++t2)
#pragma unroll
            for (int g = 0; g < 4; ++g) {
                f32x4 v;
#pragma unroll
                for (int r = 0; r < 4; ++r) v[r] = Oacc[t2][g * 4 + r];
                *(f32x4*)&Opart[orow + t2 * 32 + 8 * g + 4 * sg] = v;
            }
        if (lane < 32) {
            MLpart[(pbase + wv * 32 + lane) * 2 + 0] = m_run;
            MLpart[(pbase + wv * 32 + lane) * 2 + 1] = l_run;
        }
    }
}

// ---------------------------------------------------------------------------
// Kernel 2b: merge up to 3 partials per row, normalize, write bf16.
// ---------------------------------------------------------------------------
__global__ __launch_bounds__(256) void attn_merge_kernel(
    const float* __restrict__ Opart, const float* __restrict__ MLpart,
    __hip_bfloat16* __restrict__ O)
{
    const int idx  = blockIdx.x * 256 + threadIdx.x;
    const int d16  = idx & 3;
    const int grow = idx >> 2;             // bh*2048 + s
    const int bh   = grow >> 11;
    const int s    = grow & 2047;
    const int qb   = s >> 7;
    const int rin  = s & 127;

    const bool heavy = (qb >= 8);
    const int p  = heavy ? (15 - qb) : qb;
    const int s0 = heavy ? 0 : 3;
    const int s1 = heavy ? 1 : 4;
    const bool v1 = heavy ? true : (p >= 5);
    const bool v2 = heavy && (p <= 4);     // slot 2

    const size_t rb = (size_t)(bh * 8 + p) * 5;
    const size_t r0 = (rb + s0) * 128 + rin;
    const size_t r1 = (rb + s1) * 128 + rin;
    const size_t r2 = (rb + 2)  * 128 + rin;

    const float m0 = MLpart[r0 * 2],                 l0 = MLpart[r0 * 2 + 1];
    const float m1 = v1 ? MLpart[r1 * 2] : NEG_SENT, l1 = v1 ? MLpart[r1 * 2 + 1] : 0.f;
    const float m2 = v2 ? MLpart[r2 * 2] : NEG_SENT, l2 = v2 ? MLpart[r2 * 2 + 1] : 0.f;

    float mm = fmaxf(m0, fmaxf(m1, m2));
    const float a0 = exp2f(m0 - mm);
    const float a1 = v1 ? exp2f(m1 - mm) : 0.f;
    const float a2 = v2 ? exp2f(m2 - mm) : 0.f;
    const float inv = 1.0f / (a0 * l0 + a1 * l1 + a2 * l2);

    f32x4 o[4];
    {
        const f32x4* O0 = (const f32x4*)&Opart[r0 * 64 + d16 * 16];
#pragma unroll
        for (int v = 0; v < 4; ++v) o[v] = a0 * O0[v];
    }
    if (v1) {
        const f32x4* O1 = (const f32x4*)&Opart[r1 * 64 + d16 * 16];
#pragma unroll
        for (int v = 0; v < 4; ++v) o[v] += a1 * O1[v];
    }
    if (v2) {
        const f32x4* O2 = (const f32x4*)&Opart[r2 * 64 + d16 * 16];
#pragma unroll
        for (int v = 0; v < 4; ++v) o[v] += a2 * O2[v];
    }

    short8 out[2];
#pragma unroll
    for (int v = 0; v < 4; ++v)
#pragma unroll
        for (int jj = 0; jj < 4; ++jj)
            out[v >> 1][(v & 1) * 4 + jj] = (short)__bfloat16_as_ushort(
                __float2bfloat16(o[v][jj] * inv));

    const int b = bh >> 4, hh = bh & 15;
    __hip_bfloat16* dst = &O[((size_t)b * SEQ + s) * DMODEL + hh * 64 + d16 * 16];
    ((short8*)dst)[0] = out[0];
    ((short8*)dst)[1] = out[1];
}

// ---------------------------------------------------------------------------
// Kernel 3: out projection, 128x64 tiles, T2 swizzle + 3-buffer ring.
// (unchanged from round 16)
// ---------------------------------------------------------------------------
__global__ __launch_bounds__(256) void proj_gemm_kernel(
    const __hip_bfloat16* __restrict__ A,
    const __hip_bfloat16* __restrict__ W,
    const __hip_bfloat16* __restrict__ bias,
    void* __restrict__ outv,
    const int* __restrict__ flag)
{
    constexpr int Kd = DMODEL;
    __shared__ __align__(16) __hip_bfloat16 As[3][128 * 32];
    __shared__ __align__(16) __hip_bfloat16 Bs[3][64 * 32];

    const int tid   = threadIdx.x;
    const int lane  = tid & 63;
    const int w     = tid >> 6;
    const int mTile = blockIdx.y * 128;
    const int nTile = blockIdx.x * 64;
    const int wm    = (w >> 1) * 64;
    const int wn    = (w & 1) * 32;
    const int lm    = lane & 15;
    const int q4    = lane >> 4;
    const int lks   = (q4 ^ ((lm >> 1) & 3)) * 8;
    const bool f32out = (*flag != 0);

    f32x4 acc[4][2];
#pragma unroll
    for (int i = 0; i < 4; ++i)
#pragma unroll
        for (int j = 0; j < 2; ++j)
            acc[i][j] = (f32x4){0.f, 0.f, 0.f, 0.f};

    const int r0c = tid >> 2;
    const int r1c = (tid + 256) >> 2;
    const int cbs = ((tid & 3) ^ ((tid >> 3) & 3)) * 8;

    const __hip_bfloat16* gA0 = &A[(size_t)(mTile + r0c) * Kd + cbs];
    const __hip_bfloat16* gA1 = &A[(size_t)(mTile + r1c) * Kd + cbs];
    const __hip_bfloat16* gB0 = &W[(size_t)(nTile + r0c) * Kd + cbs];

    async16(gA0, (char*)As[0] + tid * 16);
    async16(gA1, (char*)As[0] + tid * 16 + 4096);
    async16(gB0, (char*)Bs[0] + tid * 16);
    async16(gA0 + 32, (char*)As[1] + tid * 16);
    async16(gA1 + 32, (char*)As[1] + tid * 16 + 4096);
    async16(gB0 + 32, (char*)Bs[1] + tid * 16);

    int cur = 0;
    constexpr int NIT = Kd / 32;
    for (int it = 0; it < NIT; ++it) {
        if (it + 1 < NIT) {
            asm volatile("s_waitcnt vmcnt(3)" ::: "memory");
        } else {
            asm volatile("s_waitcnt vmcnt(0)" ::: "memory");
        }
        __builtin_amdgcn_s_barrier();
        __builtin_amdgcn_sched_barrier(0);

        if (it + 2 < NIT) {
            const int slot = (cur + 2 >= 3) ? cur - 1 : cur + 2;
            const int k2 = (it + 2) * 32;
            async16(gA0 + k2, (char*)As[slot] + tid * 16);
            async16(gA1 + k2, (char*)As[slot] + tid * 16 + 4096);
            async16(gB0 + k2, (char*)Bs[slot] + tid * 16);
        }

        const __hip_bfloat16* Ac = As[cur];
        const __hip_bfloat16* Bc = Bs[cur];
        short8 a[4], b[2];
#pragma unroll
        for (int i = 0; i < 4; ++i)
            a[i] = *(const short8*)&Ac[(wm + i * 16 + lm) * 32 + lks];
#pragma unroll
        for (int j = 0; j < 2; ++j)
            b[j] = *(const short8*)&Bc[(wn + j * 16 + lm) * 32 + lks];
#pragma unroll
        for (int i = 0; i < 4; ++i)
#pragma unroll
            for (int j = 0; j < 2; ++j)
                acc[i][j] = MFMA_BF16(a[i], b[j], acc[i][j]);

        cur = (cur + 1 == 3) ? 0 : cur + 1;
    }

    const int r0 = (lane >> 4) * 4;
#pragma unroll
    for (int j = 0; j < 2; ++j) {
        const int n = nTile + wn + j * 16 + lm;
        const float bv = __bfloat162float(bias[n]);
#pragma unroll
        for (int i = 0; i < 4; ++i) {
#pragma unroll
            for (int r = 0; r < 4; ++r) {
                const size_t m = mTile + wm + i * 16 + r0 + r;
                const float v = acc[i][j][r] + bv;
                if (f32out) ((float*)outv)[m * DMODEL + n] = v;
                else ((__hip_bfloat16*)outv)[m * DMODEL + n] = __float2bfloat16(v);
            }
        }
    }
}

// ---------------------------------------------------------------------------
extern "C" void kernel_launch(void* const* d_in, const int* in_sizes, int n_in,
                              void* d_out, int out_size, void* d_ws, size_t ws_size,
                              hipStream_t stream) {
    // Workspace layout (bytes):
    // [flag:256][canon bf16][Qs][Kb][Vt][Ao][Opart f32][MLpart f32]
    const size_t OFF_CANON = 256;
    const size_t OFF_QS = OFF_CANON + (size_t)N_CANON * 2;
    const size_t OFF_KB = OFF_QS + (size_t)NTOK * DMODEL * 2;
    const size_t OFF_VT = OFF_KB + (size_t)NTOK * DMODEL * 2;
    const size_t OFF_AO = OFF_VT + (size_t)NTOK * DMODEL * 2;
    const size_t OFF_OP = OFF_AO + (size_t)NTOK * DMODEL * 2;
    const size_t OFF_ML = OFF_OP + (size_t)32 * 8 * 5 * 128 * 64 * 4;  // 41.94 MB

    char* wsb = (char*)d_ws;
    int* flag = (int*)wsb;
    __hip_bfloat16* canon = (__hip_bfloat16*)(wsb + OFF_CANON);
    __hip_bfloat16* Xc = canon;
    __hip_bfloat16* Wq = Xc + N_X;
    __hip_bfloat16* Bq = Wq + N_WQ;
    __hip_bfloat16* Wo = Bq + N_BQ;
    __hip_bfloat16* Bo = Wo + N_WO;
    __hip_bfloat16* Qs = (__hip_bfloat16*)(wsb + OFF_QS);
    __hip_bfloat16* Kb = (__hip_bfloat16*)(wsb + OFF_KB);
    __hip_bfloat16* Vt = (__hip_bfloat16*)(wsb + OFF_VT);
    __hip_bfloat16* Ao = (__hip_bfloat16*)(wsb + OFF_AO);
    float* Opart = (float*)(wsb + OFF_OP);
    float* MLpart = (float*)(wsb + OFF_ML);

    // 0) dtype detect + canonicalize (vectorized, 8 elems/thread)
    detect_kernel<<<1, 64, 0, stream>>>((const unsigned short*)d_in[1], flag);
    canon_kernel<<<(N_CANON / 8 + 255) / 256, 256, 0, stream>>>(
        d_in[0], d_in[1], d_in[2], d_in[3], d_in[4], canon, flag);

    // 1) QKV GEMM (3-buffer ring, 1 barrier/K-step)
    {
        dim3 grid(3 * DMODEL / 128, NTOK / 128);
        qkv_gemm_kernel<<<grid, 256, 0, stream>>>(Xc, Wq, Bq, Qs, Kb, Vt);
    }
    // 2) Attention: 3-way split-K, grid (32 bh, 24) = 768 WGs of 4 waves
    //    x 32 q-rows (32x32 MFMA, in-register P); 3 WGs/CU; XCD-clustered.
    {
        dim3 grid(BATCH * NHEAD, 24);
        attn_kernel<<<grid, 256, 0, stream>>>(Qs, Kb, Vt, Opart, MLpart);
        attn_merge_kernel<<<(NTOK * NHEAD * 4) / 256, 256, 0, stream>>>(
            Opart, MLpart, Ao);
    }
    // 3) Out projection: 128x64 tiles -> 512 WGs (3-buffer ring)
    {
        dim3 grid(DMODEL / 64, NTOK / 128);
        proj_gemm_kernel<<<grid, 256, 0, stream>>>(Ao, Wo, Bo, d_out, flag);
    }
}